// Round 12
// baseline (2371.322 us; speedup 1.0000x reference)
//
#include <hip/hip_runtime.h>
#include <math.h>

#define NB   8
#define TT   400
#define HH   128
#define CC   96
#define DD   4096
#define GJ   512
#define THRV (1.0f - 1e-5f)
#define XR16 40      // f16 row pad: 80 B rows, 16 B-aligned, 32 used

typedef _Float16 f16x8 __attribute__((ext_vector_type(8)));
typedef float    f32x4 __attribute__((ext_vector_type(4)));

// fast transcendentals: ~1e-7 relative error — same perturbation class as the
// fp16x3 gates (proven absmax 0.0). Phase-B divide stays IEEE (x/x==1.0 exact).
__device__ __forceinline__ float sigm(float v) { return 1.0f / (1.0f + __expf(-v)); }
__device__ __forceinline__ float ftanh(float v) {
    v = fminf(fmaxf(v, -15.f), 15.f);           // avoid inf/inf
    float u = __expf(2.0f * v);
    return (u - 1.0f) / (u + 1.0f);
}

__device__ __forceinline__ void split2(float4 u0, float4 u1, f16x8& hi, f16x8& lo) {
    float x[8] = {u0.x, u0.y, u0.z, u0.w, u1.x, u1.y, u1.z, u1.w};
    #pragma unroll
    for (int e = 0; e < 8; ++e) {
        _Float16 h = (_Float16)x[e];
        hi[e] = h;
        lo[e] = (_Float16)(x[e] - (float)h);
    }
}
__device__ __forceinline__ void split1(float x, _Float16& hi, _Float16& lo) {
    hi = (_Float16)x;
    lo = (_Float16)(x - (float)hi);
}

__global__ __launch_bounds__(512, 2)
void gru_title(const float* __restrict__ img,
               const float* __restrict__ l1w,
               const float* __restrict__ l1b,
               const float* __restrict__ wih,
               const float* __restrict__ whh,
               const float* __restrict__ bih,
               const float* __restrict__ bhh,
               const float* __restrict__ l2w,
               const float* __restrict__ l2b,
               float* __restrict__ out,
               float* __restrict__ lens)
{
    // x[m][k] at row 16*((k>>3)&3)+m, f16 col 8*(k>>5)+(k&7)  (A-frag swizzle)
    __shared__ alignas(16) _Float16 xh[2][64][XR16];  // split-hi of h
    __shared__ alignas(16) _Float16 xlo[2][64][XR16]; // split-lo of h
    __shared__ alignas(16) _Float16 lh[2][64][XR16];  // split-hi of leaky(h)
    __shared__ alignas(16) _Float16 llo[2][64][XR16]; // split-lo of leaky(h)
    __shared__ alignas(16) float xs0[NB][HH];         // x0 linear (t=0 scalar path)
    __shared__ alignas(16) float gs[NB][GJ];          // t=0 gate pre-activations
    __shared__ alignas(16) float chs[2][NB][CC];      // chars, parity-buffered
    __shared__ int sh_st[4];                          // stable flags, 4-slot rotation

    const int tid  = threadIdx.x;
    const int b0   = blockIdx.x * NB;
    const int w    = tid >> 6;
    const int lane = tid & 63;
    const int lm   = lane & 15;
    const int lq   = lane >> 4;

    // ---- t=0 scalar-path bias ----
    float bj0;
    if (tid < 256)      bj0 = bih[tid] + bhh[tid];
    else if (tid < 384) bj0 = bih[tid];
    else                bj0 = bhh[tid - 128];

    // ---- gate weight fragments: col j = 128*nt + 16*w + lm (nt=r,z,i_n,h_n) ----
    f16x8 bgh[4][4], bgl[4][4];
    float gb[4];
    {
        const int j0 = 16 * w + lm;
        #pragma unroll
        for (int nt = 0; nt < 2; ++nt) {
            const int j = j0 + 128 * nt;
            gb[nt] = bih[j] + bhh[j];
            const float* r0 = wih + (size_t)j * HH;
            const float* r1 = whh + (size_t)j * HH;
            #pragma unroll
            for (int kt = 0; kt < 4; ++kt) {
                const int k0 = 32 * kt + 8 * lq;
                float4 u0 = *(const float4*)(r0 + k0);
                float4 u1 = *(const float4*)(r0 + k0 + 4);
                float4 e0 = *(const float4*)(r1 + k0);
                float4 e1 = *(const float4*)(r1 + k0 + 4);
                u0.x += e0.x; u0.y += e0.y; u0.z += e0.z; u0.w += e0.w;
                u1.x += e1.x; u1.y += e1.y; u1.z += e1.z; u1.w += e1.w;
                split2(u0, u1, bgh[nt][kt], bgl[nt][kt]);
            }
        }
        {
            const int j = j0 + 256;
            gb[2] = bih[j];
            const float* r0 = wih + (size_t)j * HH;
            #pragma unroll
            for (int kt = 0; kt < 4; ++kt) {
                const int k0 = 32 * kt + 8 * lq;
                split2(*(const float4*)(r0 + k0), *(const float4*)(r0 + k0 + 4),
                       bgh[2][kt], bgl[2][kt]);
            }
        }
        {
            const int j = j0 + 256;
            gb[3] = bhh[j];
            const float* r0 = whh + (size_t)j * HH;
            #pragma unroll
            for (int kt = 0; kt < 4; ++kt) {
                const int k0 = 32 * kt + 8 * lq;
                split2(*(const float4*)(r0 + k0), *(const float4*)(r0 + k0 + 4),
                       bgh[3][kt], bgl[3][kt]);
            }
        }
    }

    // ---- chars weight fragments: waves 0..5, col n = 16w + lm ----
    f16x8 bch[4], bcl[4];
    float cb = 0.f;
    if (w < 6) {
        const int n = 16 * w + lm;
        cb = l2b[n];
        #pragma unroll
        for (int kt = 0; kt < 4; ++kt) {
            const int k0 = 32 * kt + 8 * lq;
            split2(*(const float4*)(l2w + (size_t)n * HH + k0),
                   *(const float4*)(l2w + (size_t)n * HH + k0 + 4),
                   bch[kt], bcl[kt]);
        }
    }

    if (tid < 4) sh_st[tid] = 1;

    // ---- prologue: x0 = leaky(img @ l1w.T + l1b), 2 rows per thread ----
    {
        const int c  = tid & 127;
        const int mh = tid >> 7;
        const int r0 = 2 * mh, r1 = r0 + 1;
        const float4* xp0 = (const float4*)(img + (size_t)(b0 + r0) * DD);
        const float4* xp1 = (const float4*)(img + (size_t)(b0 + r1) * DD);
        const float4* wp  = (const float4*)(l1w + (size_t)c * DD);
        float a0 = 0.f, b0v = 0.f, a1 = 0.f, b1v = 0.f;
        #pragma unroll 4
        for (int k = 0; k < DD/4; k += 2) {
            float4 w0 = wp[k],  w1 = wp[k+1];
            float4 u0 = xp0[k], u1 = xp0[k+1];
            float4 v0 = xp1[k], v1 = xp1[k+1];
            a0  += w0.x*u0.x + w0.y*u0.y + w0.z*u0.z + w0.w*u0.w;
            b0v += w1.x*u1.x + w1.y*u1.y + w1.z*u1.z + w1.w*u1.w;
            a1  += w0.x*v0.x + w0.y*v0.y + w0.z*v0.z + w0.w*v0.w;
            b1v += w1.x*v1.x + w1.y*v1.y + w1.z*v1.z + w1.w*v1.w;
        }
        float h0 = a0 + b0v + l1b[c];
        float h1 = a1 + b1v + l1b[c];
        xs0[r0][c] = (h0 >= 0.f) ? h0 : 0.01f*h0;
        xs0[r1][c] = (h1 >= 0.f) ? h1 : 0.01f*h1;
    }
    __syncthreads();

    // owned hidden index (writers lq<2): col iC, rows 4*lq+reg
    const int iC   = 16 * w + lm;
    const int rB   = 16 * ((iC >> 3) & 3);     // row base 16*qC
    const int xoff = 8 * (iC >> 5) + (iC & 7); // f16 col offset

    float hreg[4];    // h(t)
    float hreg2[4];   // h(t-2) (period-2 detection)
    int  len   = TT;
    bool found = false;
    int  tex   = TT;

    // ===== single-barrier step: S(t) = gates(t) + chars(t-1) + scatter(t-2) + nonlin =====
    for (int t = 0; t < TT; ++t) {
        const int pr = (t + 1) & 1;   // (t-1)&1 : read slot for x/l
        const int pc = t & 1;         // write slot; also (t-2)&1 for chs scatter

        if (t == 0) {
            float acc[NB];
            #pragma unroll
            for (int m = 0; m < NB; ++m) acc[m] = bj0;
            if (tid < 384) {
                const float4* wp = (const float4*)(wih + (size_t)tid * HH);
                #pragma unroll
                for (int k = 0; k < HH/4; ++k) {
                    float4 wv = wp[k];
                    #pragma unroll
                    for (int m = 0; m < NB; ++m) {
                        float4 x = *(const float4*)&xs0[m][4*k];
                        acc[m] += wv.x*x.x + wv.y*x.y + wv.z*x.z + wv.w*x.w;
                    }
                }
            }
            #pragma unroll
            for (int m = 0; m < NB; ++m) gs[m][tid] = acc[m];
            __syncthreads();
            if (lq < 2) {
                #pragma unroll
                for (int reg = 0; reg < 4; ++reg) {
                    const int m = 4*lq + reg;
                    float r = sigm(gs[m][iC]);
                    float z = sigm(gs[m][HH + iC]);
                    float n = ftanh(gs[m][2*HH + iC] + r * gs[m][3*HH + iC]);
                    float h = (1.f - z) * n;          // hp = 0
                    hreg[reg]  = h;
                    hreg2[reg] = 0.f;
                    _Float16 a, b;
                    split1(h, a, b);
                    xh[0][rB + m][xoff] = a;  xlo[0][rB + m][xoff] = b;
                    float lv = (h >= 0.f) ? h : 0.01f * h;
                    split1(lv, a, b);
                    lh[0][rB + m][xoff] = a;  llo[0][rB + m][xoff] = b;
                }
            }
        } else {
            // ---- gates(t): reads x slot pr ----
            f32x4 acc[4];
            #pragma unroll
            for (int nt = 0; nt < 4; ++nt) {
                f32x4 c0 = {gb[nt], gb[nt], gb[nt], gb[nt]};
                acc[nt] = c0;
            }
            #pragma unroll
            for (int kt = 0; kt < 4; ++kt) {
                f16x8 ah = *(const f16x8*)&xh [pr][16*lq + lm][8*kt];
                f16x8 al = *(const f16x8*)&xlo[pr][16*lq + lm][8*kt];
                #pragma unroll
                for (int nt = 0; nt < 4; ++nt) {
                    acc[nt] = __builtin_amdgcn_mfma_f32_16x16x32_f16(ah, bgh[nt][kt], acc[nt], 0, 0, 0);
                    acc[nt] = __builtin_amdgcn_mfma_f32_16x16x32_f16(al, bgh[nt][kt], acc[nt], 0, 0, 0);
                    acc[nt] = __builtin_amdgcn_mfma_f32_16x16x32_f16(ah, bgl[nt][kt], acc[nt], 0, 0, 0);
                }
            }
            // ---- chars(t-1): reads l slot pr, writes chs slot pr ----
            if (w < 6) {
                f32x4 cacc = {cb, cb, cb, cb};
                #pragma unroll
                for (int kt = 0; kt < 4; ++kt) {
                    f16x8 ch = *(const f16x8*)&lh [pr][16*lq + lm][8*kt];
                    f16x8 cl = *(const f16x8*)&llo[pr][16*lq + lm][8*kt];
                    cacc = __builtin_amdgcn_mfma_f32_16x16x32_f16(ch, bch[kt], cacc, 0, 0, 0);
                    cacc = __builtin_amdgcn_mfma_f32_16x16x32_f16(cl, bch[kt], cacc, 0, 0, 0);
                    cacc = __builtin_amdgcn_mfma_f32_16x16x32_f16(ch, bcl[kt], cacc, 0, 0, 0);
                }
                if (lq < 2) {
                    #pragma unroll
                    for (int reg = 0; reg < 4; ++reg)
                        chs[pr][4*lq + reg][16*w + lm] = cacc[reg];
                }
            }
            // ---- scatter chars(t-2): reads chs slot pc (== (t-2)&1) ----
            if (t >= 2) {
                const float* cr = &chs[pc][w][0];
                float v0 = cr[lane];
                float v1 = (lane < 32) ? cr[64 + lane] : -INFINITY;
                float mx = fmaxf(v0, v1);
                #pragma unroll
                for (int s = 32; s > 0; s >>= 1) mx = fmaxf(mx, __shfl_xor(mx, s, 64));
                float q0 = v0 / mx;
                size_t base = ((size_t)(b0 + w) * TT + (t - 2)) * CC;
                if (q0 > THRV) out[base + lane] = q0;
                if (lane < 32) {
                    float q1 = v1 / mx;
                    if (q1 > THRV) out[base + 64 + lane] = q1;
                }
                float q52 = __shfl(q0, 52, 64);
                if (!found && q52 == 1.0f) { found = true; len = t - 1; }  // time t-2
            }
            // ---- fused nonlinearity, writes x/l slot pc; period-2 detect ----
            if (lq < 2) {
                bool changed = (t < 2);
                #pragma unroll
                for (int reg = 0; reg < 4; ++reg) {
                    const int m = 4*lq + reg;
                    float r  = sigm(acc[0][reg]);
                    float z  = sigm(acc[1][reg]);
                    float n  = ftanh(acc[2][reg] + r * acc[3][reg]);
                    float hp = hreg[reg];
                    float h  = (1.f - z) * n + z * hp;
                    changed |= (__float_as_uint(h) != __float_as_uint(hreg2[reg]));
                    hreg2[reg] = hp;
                    hreg[reg]  = h;
                    _Float16 a, b;
                    split1(h, a, b);
                    xh[pc][rB + m][xoff] = a;  xlo[pc][rB + m][xoff] = b;
                    float lv = (h >= 0.f) ? h : 0.01f * h;
                    split1(lv, a, b);
                    lh[pc][rB + m][xoff] = a;  llo[pc][rB + m][xoff] = b;
                }
                if (changed) sh_st[t & 3] = 0;   // benign multi-writer race
            }
        }
        if (tid == 0) sh_st[(t + 2) & 3] = 1;   // slot for t+2; 2 barriers ahead of its writers
        __syncthreads();
        if (t >= 2 && sh_st[t & 3]) { tex = t; break; }
        // slot hazards all 1-barrier separated: x/l write pc vs read pr; chs write pr
        // vs read pc; next phase flips parity.
    }

    if (tex == TT) {
        // natural end: pending scatter chars(TT-2) + compute/scatter chars(TT-1)
        const int pl = (TT - 1) & 1;
        if (w < 6) {
            f32x4 cacc = {cb, cb, cb, cb};
            #pragma unroll
            for (int kt = 0; kt < 4; ++kt) {
                f16x8 ch = *(const f16x8*)&lh [pl][16*lq + lm][8*kt];
                f16x8 cl = *(const f16x8*)&llo[pl][16*lq + lm][8*kt];
                cacc = __builtin_amdgcn_mfma_f32_16x16x32_f16(ch, bch[kt], cacc, 0, 0, 0);
                cacc = __builtin_amdgcn_mfma_f32_16x16x32_f16(cl, bch[kt], cacc, 0, 0, 0);
                cacc = __builtin_amdgcn_mfma_f32_16x16x32_f16(ch, bcl[kt], cacc, 0, 0, 0);
            }
            if (lq < 2) {
                #pragma unroll
                for (int reg = 0; reg < 4; ++reg)
                    chs[pl][4*lq + reg][16*w + lm] = cacc[reg];
            }
        }
        {   // scatter chars(TT-2) from chs[(TT-2)&1]
            const float* cr = &chs[TT & 1][w][0];
            float v0 = cr[lane];
            float v1 = (lane < 32) ? cr[64 + lane] : -INFINITY;
            float mx = fmaxf(v0, v1);
            #pragma unroll
            for (int s = 32; s > 0; s >>= 1) mx = fmaxf(mx, __shfl_xor(mx, s, 64));
            float q0 = v0 / mx;
            size_t base = ((size_t)(b0 + w) * TT + (TT - 2)) * CC;
            if (q0 > THRV) out[base + lane] = q0;
            if (lane < 32) {
                float q1 = v1 / mx;
                if (q1 > THRV) out[base + 64 + lane] = q1;
            }
            float q52 = __shfl(q0, 52, 64);
            if (!found && q52 == 1.0f) { found = true; len = TT - 1; }
        }
        __syncthreads();
        {   // scatter chars(TT-1)
            const float* cr = &chs[pl][w][0];
            float v0 = cr[lane];
            float v1 = (lane < 32) ? cr[64 + lane] : -INFINITY;
            float mx = fmaxf(v0, v1);
            #pragma unroll
            for (int s = 32; s > 0; s >>= 1) mx = fmaxf(mx, __shfl_xor(mx, s, 64));
            float q0 = v0 / mx;
            size_t base = ((size_t)(b0 + w) * TT + (TT - 1)) * CC;
            if (q0 > THRV) out[base + lane] = q0;
            if (lane < 32) {
                float q1 = v1 / mx;
                if (q1 > THRV) out[base + 64 + lane] = q1;
            }
            float q52 = __shfl(q0, 52, 64);
            if (!found && q52 == 1.0f) { found = true; len = TT; }
        }
    } else {
        // period-<=2 cycle from tex: h(tex)==h(tex-2) => chars(u)=chs[u&1] for u>=tex-2.
        // Scattered so far: 0..tex-2. Pending: chars(tex-1) (argmax-check here),
        // then replicate the two cycle vectors stride-2 for u in [tex, TT).
        {
            const float* cr = &chs[(tex + 1) & 1][w][0];   // (tex-1)&1
            float v0 = cr[lane];
            float v1 = (lane < 32) ? cr[64 + lane] : -INFINITY;
            float mx = fmaxf(v0, v1);
            #pragma unroll
            for (int s = 32; s > 0; s >>= 1) mx = fmaxf(mx, __shfl_xor(mx, s, 64));
            float q0 = v0 / mx;
            size_t base = ((size_t)(b0 + w) * TT + (tex - 1)) * CC;
            if (q0 > THRV) out[base + lane] = q0;
            if (lane < 32) {
                float q1 = v1 / mx;
                if (q1 > THRV) out[base + 64 + lane] = q1;
            }
            float q52 = __shfl(q0, 52, 64);
            if (!found && q52 == 1.0f) { found = true; len = tex; }
        }
        size_t rowbase = (size_t)(b0 + w) * TT * CC;
        #pragma unroll
        for (int p = 0; p < 2; ++p) {
            const float* cr = &chs[p][w][0];
            float v0 = cr[lane];
            float v1 = (lane < 32) ? cr[64 + lane] : -INFINITY;
            float mx = fmaxf(v0, v1);
            #pragma unroll
            for (int s = 32; s > 0; s >>= 1) mx = fmaxf(mx, __shfl_xor(mx, s, 64));
            const int u0 = tex + (((tex & 1) == p) ? 0 : 1);
            float q0 = v0 / mx;
            if (q0 > THRV)
                for (int u = u0; u < TT; u += 2) out[rowbase + (size_t)u * CC + lane] = q0;
            if (lane < 32) {
                float q1 = v1 / mx;
                if (q1 > THRV)
                    for (int u = u0; u < TT; u += 2) out[rowbase + (size_t)u * CC + 64 + lane] = q1;
            }
        }
        // lens: both cycle vectors argmax-checked at times tex-2 and tex-1; final.
    }

    if (lane == 0) lens[b0 + w] = (float)len;
}

extern "C" void kernel_launch(void* const* d_in, const int* in_sizes, int n_in,
                              void* d_out, int out_size, void* d_ws, size_t ws_size,
                              hipStream_t stream)
{
    const float* img = (const float*)d_in[0];
    const float* l1w = (const float*)d_in[1];
    const float* l1b = (const float*)d_in[2];
    const float* wih = (const float*)d_in[3];
    const float* whh = (const float*)d_in[4];
    const float* bih = (const float*)d_in[5];
    const float* bhh = (const float*)d_in[6];
    const float* l2w = (const float*)d_in[7];
    const float* l2b = (const float*)d_in[8];

    float* out  = (float*)d_out;
    float* lens = out + (size_t)2048 * TT * CC;

    // titles is ~99% zeros: clear everything, kernel scatters only survivors.
    hipMemsetAsync(d_out, 0, (size_t)out_size * sizeof(float), stream);

    gru_title<<<dim3(2048 / NB), dim3(512), 0, stream>>>(
        img, l1w, l1b, wih, whh, bih, bhh, l2w, l2b, out, lens);
}

// Round 13
// 2040.793 us; speedup vs baseline: 1.1620x; 1.1620x over previous
//
#include <hip/hip_runtime.h>
#include <math.h>

#define NB   8
#define TT   400
#define HH   128
#define CC   96
#define DD   4096
#define THRV (1.0f - 1e-5f)
#define XR16 40      // f16 row pad: 80 B rows, 16 B-aligned, 32 used

typedef _Float16 f16x8 __attribute__((ext_vector_type(8)));
typedef float    f32x4 __attribute__((ext_vector_type(4)));

// fast transcendentals (~1e-7 rel) — proven absmax 0.0 in R12.
__device__ __forceinline__ float sigm(float v) { return 1.0f / (1.0f + __expf(-v)); }
__device__ __forceinline__ float ftanh(float v) {
    v = fminf(fmaxf(v, -15.f), 15.f);
    float u = __expf(2.0f * v);
    return (u - 1.0f) / (u + 1.0f);
}

__device__ __forceinline__ void split2(float4 u0, float4 u1, f16x8& hi, f16x8& lo) {
    float x[8] = {u0.x, u0.y, u0.z, u0.w, u1.x, u1.y, u1.z, u1.w};
    #pragma unroll
    for (int e = 0; e < 8; ++e) {
        _Float16 h = (_Float16)x[e];
        hi[e] = h;
        lo[e] = (_Float16)(x[e] - (float)h);
    }
}
__device__ __forceinline__ void split1(float x, _Float16& hi, _Float16& lo) {
    hi = (_Float16)x;
    lo = (_Float16)(x - (float)hi);
}

__global__ __launch_bounds__(1024)
void gru_title(const float* __restrict__ img,
               const float* __restrict__ l1w,
               const float* __restrict__ l1b,
               const float* __restrict__ wih,
               const float* __restrict__ whh,
               const float* __restrict__ bih,
               const float* __restrict__ bhh,
               const float* __restrict__ l2w,
               const float* __restrict__ l2b,
               float* __restrict__ out,
               float* __restrict__ lens)
{
    // x[m][k] at row 16*((k>>3)&3)+m, f16 col 8*(k>>5)+(k&7)  (A-frag swizzle)
    __shared__ alignas(16) _Float16 xh [2][64][XR16];
    __shared__ alignas(16) _Float16 xlo[2][64][XR16];
    __shared__ alignas(16) _Float16 lh [2][64][XR16];
    __shared__ alignas(16) _Float16 llo[2][64][XR16];
    __shared__ alignas(16) float xs0[NB][HH];       // x0 linear (t=0 scalar path)
    __shared__ alignas(16) float gs[NB][HH][4];     // gate pre-act, [m][i][nt]
    __shared__ alignas(16) float chs[2][NB][CC];    // chars, parity-buffered
    __shared__ alignas(16) _Float16 bclS[6][4][4][16][8]; // chars lo-weights (24 KB)
    __shared__ int sh_st[4];                        // stable flags, 4-slot rotation

    const int tid  = threadIdx.x;
    const int b0   = blockIdx.x * NB;
    const int w    = tid >> 6;     // wave 0..15
    const int lane = tid & 63;
    const int lm   = lane & 15;
    const int lq   = lane >> 4;

    // ---- gate weight fragments: wave w owns cols j = 32w + 16*tau + lm ----
    f16x8 bgh[2][4], bgl[2][4];
    float gb[2];
    #pragma unroll
    for (int tau = 0; tau < 2; ++tau) {
        const int j = 32 * w + 16 * tau + lm;
        const float* r0;
        const float* r1 = nullptr;
        if (j < 256)      { r0 = wih + (size_t)j * HH; r1 = whh + (size_t)j * HH;
                            gb[tau] = bih[j] + bhh[j]; }
        else if (j < 384) { r0 = wih + (size_t)j * HH;            gb[tau] = bih[j]; }
        else              { r0 = whh + (size_t)(j - 128) * HH;    gb[tau] = bhh[j - 128]; }
        #pragma unroll
        for (int kt = 0; kt < 4; ++kt) {
            const int k0 = 32 * kt + 8 * lq;
            float4 u0 = *(const float4*)(r0 + k0);
            float4 u1 = *(const float4*)(r0 + k0 + 4);
            if (r1) {   // wave-uniform (j<256 <=> w<8)
                float4 e0 = *(const float4*)(r1 + k0);
                float4 e1 = *(const float4*)(r1 + k0 + 4);
                u0.x += e0.x; u0.y += e0.y; u0.z += e0.z; u0.w += e0.w;
                u1.x += e1.x; u1.y += e1.y; u1.z += e1.z; u1.w += e1.w;
            }
            split2(u0, u1, bgh[tau][kt], bgl[tau][kt]);
        }
    }

    // ---- chars: waves 10..15 own col n = 16*(w-10)+lm; hi in regs, lo in LDS ----
    const int ct = w - 10;
    f16x8 bch[4];
    float cb = 0.f;
    if (w >= 10) {
        const int n = 16 * ct + lm;
        cb = l2b[n];
        #pragma unroll
        for (int kt = 0; kt < 4; ++kt) {
            const int k0 = 32 * kt + 8 * lq;
            float4 u0 = *(const float4*)(l2w + (size_t)n * HH + k0);
            float4 u1 = *(const float4*)(l2w + (size_t)n * HH + k0 + 4);
            f16x8 hi, lo;
            split2(u0, u1, hi, lo);
            bch[kt] = hi;
        }
    }
    // stash chars lo-weights in LDS (all threads help)
    for (int idx = tid; idx < 6 * 4 * 4 * 16; idx += 1024) {
        int t_  = idx;
        int lm_ = t_ & 15; t_ >>= 4;
        int lq_ = t_ & 3;  t_ >>= 2;
        int kt_ = t_ & 3;  t_ >>= 2;
        int ct_ = t_;                       // 0..5
        const int n  = 16 * ct_ + lm_;
        const int k0 = 32 * kt_ + 8 * lq_;
        #pragma unroll
        for (int e = 0; e < 8; ++e) {
            float v = l2w[(size_t)n * HH + k0 + e];
            _Float16 hi = (_Float16)v;
            bclS[ct_][kt_][lq_][lm_][e] = (_Float16)(v - (float)hi);
        }
    }

    // ---- t=0 scalar-path bias (thread = gate column, tid<512) ----
    float bj0 = 0.f;
    if (tid < 256)      bj0 = bih[tid] + bhh[tid];
    else if (tid < 384) bj0 = bih[tid];
    else if (tid < 512) bj0 = bhh[tid - 128];

    if (tid < 4) sh_st[tid] = 1;

    // ---- prologue: x0 = leaky(img @ l1w.T + l1b), 1 (row,col) per thread ----
    {
        const int c = tid & 127;
        const int m = tid >> 7;              // 0..7
        const float4* xp = (const float4*)(img + (size_t)(b0 + m) * DD);
        const float4* wp = (const float4*)(l1w + (size_t)c * DD);
        float a0 = 0.f, a1 = 0.f;
        #pragma unroll 4
        for (int k = 0; k < DD/4; k += 2) {
            float4 w0 = wp[k], w1 = wp[k+1];
            float4 u0 = xp[k], u1 = xp[k+1];
            a0 += w0.x*u0.x + w0.y*u0.y + w0.z*u0.z + w0.w*u0.w;
            a1 += w1.x*u1.x + w1.y*u1.y + w1.z*u1.z + w1.w*u1.w;
        }
        float h0 = a0 + a1 + l1b[c];
        xs0[m][c] = (h0 >= 0.f) ? h0 : 0.01f*h0;
    }
    __syncthreads();

    // nonlin ownership: thread -> (mN, iN), one hidden element
    const int iN  = tid & 127;
    const int mN  = tid >> 7;
    const int rB  = 16 * ((iN >> 3) & 3);      // A-swizzle row base
    const int xof = 8 * (iN >> 5) + (iN & 7);  // f16 col offset

    float hreg  = 0.f;   // h(t)  at owned element
    float hreg2 = 0.f;   // h(t-2) (period-2 detection)
    int  len   = TT;
    bool found = false;
    int  tex   = TT;

    for (int t = 0; t < TT; ++t) {
        const int pr = (t + 1) & 1;   // (t-1)&1 : read slot
        const int pc = t & 1;         // write slot; == (t-2)&1 for chs scatter

        // ================= phase A =================
        if (t == 0) {
            if (tid < 512) {
                float acc[NB];
                #pragma unroll
                for (int m = 0; m < NB; ++m) acc[m] = bj0;
                if (tid < 384) {
                    const float4* wp = (const float4*)(wih + (size_t)tid * HH);
                    #pragma unroll
                    for (int k = 0; k < HH/4; ++k) {
                        float4 wv = wp[k];
                        #pragma unroll
                        for (int m = 0; m < NB; ++m) {
                            float4 x = *(const float4*)&xs0[m][4*k];
                            acc[m] += wv.x*x.x + wv.y*x.y + wv.z*x.z + wv.w*x.w;
                        }
                    }
                }
                const int i_ = tid & 127, nt_ = tid >> 7;
                #pragma unroll
                for (int m = 0; m < NB; ++m) gs[m][i_][nt_] = acc[m];
            }
        } else {
            // ---- gates(t): 2 n-tiles, reads x slot pr ----
            f32x4 acc[2];
            #pragma unroll
            for (int tau = 0; tau < 2; ++tau) {
                f32x4 c0 = {gb[tau], gb[tau], gb[tau], gb[tau]};
                acc[tau] = c0;
            }
            #pragma unroll
            for (int kt = 0; kt < 4; ++kt) {
                f16x8 ah = *(const f16x8*)&xh [pr][16*lq + lm][8*kt];
                f16x8 al = *(const f16x8*)&xlo[pr][16*lq + lm][8*kt];
                #pragma unroll
                for (int tau = 0; tau < 2; ++tau) {
                    acc[tau] = __builtin_amdgcn_mfma_f32_16x16x32_f16(ah, bgh[tau][kt], acc[tau], 0, 0, 0);
                    acc[tau] = __builtin_amdgcn_mfma_f32_16x16x32_f16(al, bgh[tau][kt], acc[tau], 0, 0, 0);
                    acc[tau] = __builtin_amdgcn_mfma_f32_16x16x32_f16(ah, bgl[tau][kt], acc[tau], 0, 0, 0);
                }
            }
            if (lq < 2) {
                #pragma unroll
                for (int tau = 0; tau < 2; ++tau) {
                    const int j = 32*w + 16*tau + lm;
                    #pragma unroll
                    for (int reg = 0; reg < 4; ++reg)
                        gs[4*lq + reg][j & 127][j >> 7] = acc[tau][reg];
                }
            }
            // ---- chars(t-1): waves 10..15, reads l slot pr ----
            if (w >= 10) {
                f32x4 cacc = {cb, cb, cb, cb};
                #pragma unroll
                for (int kt = 0; kt < 4; ++kt) {
                    f16x8 ch = *(const f16x8*)&lh [pr][16*lq + lm][8*kt];
                    f16x8 cl = *(const f16x8*)&llo[pr][16*lq + lm][8*kt];
                    f16x8 wl = *(const f16x8*)&bclS[ct][kt][lq][lm][0];
                    cacc = __builtin_amdgcn_mfma_f32_16x16x32_f16(ch, bch[kt], cacc, 0, 0, 0);
                    cacc = __builtin_amdgcn_mfma_f32_16x16x32_f16(cl, bch[kt], cacc, 0, 0, 0);
                    cacc = __builtin_amdgcn_mfma_f32_16x16x32_f16(ch, wl,      cacc, 0, 0, 0);
                }
                if (lq < 2) {
                    #pragma unroll
                    for (int reg = 0; reg < 4; ++reg)
                        chs[pr][4*lq + reg][16*ct + lm] = cacc[reg];
                }
            }
            // ---- scatter chars(t-2): waves 0..7, reads chs slot pc ----
            if (t >= 2 && w < 8) {
                const float* cr = &chs[pc][w][0];
                float v0 = cr[lane];
                float v1 = (lane < 32) ? cr[64 + lane] : -INFINITY;
                float mx = fmaxf(v0, v1);
                #pragma unroll
                for (int s = 32; s > 0; s >>= 1) mx = fmaxf(mx, __shfl_xor(mx, s, 64));
                float q0 = v0 / mx;
                size_t base = ((size_t)(b0 + w) * TT + (t - 2)) * CC;
                if (q0 > THRV) out[base + lane] = q0;
                if (lane < 32) {
                    float q1 = v1 / mx;
                    if (q1 > THRV) out[base + 64 + lane] = q1;
                }
                float q52 = __shfl(q0, 52, 64);
                if (!found && q52 == 1.0f) { found = true; len = t - 1; }  // time t-2
            }
        }
        __syncthreads();   // bar1

        // ================= phase B: nonlin, 1 element/thread =================
        {
            float4 g4 = *(const float4*)&gs[mN][iN][0];
            float r  = sigm(g4.x);
            float z  = sigm(g4.y);
            float n  = ftanh(g4.z + r * g4.w);
            float hp = (t == 0) ? 0.f : hreg;
            float h  = (1.f - z) * n + z * hp;
            bool changed = (t < 2) | (__float_as_uint(h) != __float_as_uint(hreg2));
            hreg2 = hp;
            hreg  = h;
            _Float16 a, b;
            split1(h, a, b);
            xh [pc][rB + mN][xof] = a;  xlo[pc][rB + mN][xof] = b;
            float lv = (h >= 0.f) ? h : 0.01f * h;
            split1(lv, a, b);
            lh [pc][rB + mN][xof] = a;  llo[pc][rB + mN][xof] = b;
            if (changed) sh_st[t & 3] = 0;   // benign multi-writer race
        }
        if (tid == 0) sh_st[(t + 2) & 3] = 1;   // slot for t+2; 2 barriers from its writers
        __syncthreads();   // bar2
        if (t >= 2 && sh_st[t & 3]) { tex = t; break; }
    }

    if (tex == TT) {
        // natural end: scatter chars(TT-2); compute + scatter chars(TT-1)
        const int pl = (TT - 1) & 1;
        if (w >= 10) {
            f32x4 cacc = {cb, cb, cb, cb};
            #pragma unroll
            for (int kt = 0; kt < 4; ++kt) {
                f16x8 ch = *(const f16x8*)&lh [pl][16*lq + lm][8*kt];
                f16x8 cl = *(const f16x8*)&llo[pl][16*lq + lm][8*kt];
                f16x8 wl = *(const f16x8*)&bclS[ct][kt][lq][lm][0];
                cacc = __builtin_amdgcn_mfma_f32_16x16x32_f16(ch, bch[kt], cacc, 0, 0, 0);
                cacc = __builtin_amdgcn_mfma_f32_16x16x32_f16(cl, bch[kt], cacc, 0, 0, 0);
                cacc = __builtin_amdgcn_mfma_f32_16x16x32_f16(ch, wl,      cacc, 0, 0, 0);
            }
            if (lq < 2) {
                #pragma unroll
                for (int reg = 0; reg < 4; ++reg)
                    chs[pl][4*lq + reg][16*ct + lm] = cacc[reg];
            }
        }
        if (w < 8) {   // scatter chars(TT-2) from chs[TT&1]
            const float* cr = &chs[TT & 1][w][0];
            float v0 = cr[lane];
            float v1 = (lane < 32) ? cr[64 + lane] : -INFINITY;
            float mx = fmaxf(v0, v1);
            #pragma unroll
            for (int s = 32; s > 0; s >>= 1) mx = fmaxf(mx, __shfl_xor(mx, s, 64));
            float q0 = v0 / mx;
            size_t base = ((size_t)(b0 + w) * TT + (TT - 2)) * CC;
            if (q0 > THRV) out[base + lane] = q0;
            if (lane < 32) {
                float q1 = v1 / mx;
                if (q1 > THRV) out[base + 64 + lane] = q1;
            }
            float q52 = __shfl(q0, 52, 64);
            if (!found && q52 == 1.0f) { found = true; len = TT - 1; }
        }
        __syncthreads();
        if (w < 8) {   // scatter chars(TT-1)
            const float* cr = &chs[pl][w][0];
            float v0 = cr[lane];
            float v1 = (lane < 32) ? cr[64 + lane] : -INFINITY;
            float mx = fmaxf(v0, v1);
            #pragma unroll
            for (int s = 32; s > 0; s >>= 1) mx = fmaxf(mx, __shfl_xor(mx, s, 64));
            float q0 = v0 / mx;
            size_t base = ((size_t)(b0 + w) * TT + (TT - 1)) * CC;
            if (q0 > THRV) out[base + lane] = q0;
            if (lane < 32) {
                float q1 = v1 / mx;
                if (q1 > THRV) out[base + 64 + lane] = q1;
            }
            float q52 = __shfl(q0, 52, 64);
            if (!found && q52 == 1.0f) { found = true; len = TT; }
        }
    } else if (w < 8) {
        // period-<=2 cycle from tex: chars(u) = chs[u&1] for u >= tex-2.
        // Scattered so far: 0..tex-2. Argmax-check chars(tex-1), then stride-2 fill.
        {
            const float* cr = &chs[(tex + 1) & 1][w][0];   // chars(tex-1)
            float v0 = cr[lane];
            float v1 = (lane < 32) ? cr[64 + lane] : -INFINITY;
            float mx = fmaxf(v0, v1);
            #pragma unroll
            for (int s = 32; s > 0; s >>= 1) mx = fmaxf(mx, __shfl_xor(mx, s, 64));
            float q0 = v0 / mx;
            size_t base = ((size_t)(b0 + w) * TT + (tex - 1)) * CC;
            if (q0 > THRV) out[base + lane] = q0;
            if (lane < 32) {
                float q1 = v1 / mx;
                if (q1 > THRV) out[base + 64 + lane] = q1;
            }
            float q52 = __shfl(q0, 52, 64);
            if (!found && q52 == 1.0f) { found = true; len = tex; }
        }
        size_t rowbase = (size_t)(b0 + w) * TT * CC;
        #pragma unroll
        for (int p = 0; p < 2; ++p) {
            const float* cr = &chs[p][w][0];
            float v0 = cr[lane];
            float v1 = (lane < 32) ? cr[64 + lane] : -INFINITY;
            float mx = fmaxf(v0, v1);
            #pragma unroll
            for (int s = 32; s > 0; s >>= 1) mx = fmaxf(mx, __shfl_xor(mx, s, 64));
            const int u0 = tex + (((tex & 1) == p) ? 0 : 1);
            float q0 = v0 / mx;
            if (q0 > THRV)
                for (int u = u0; u < TT; u += 2) out[rowbase + (size_t)u * CC + lane] = q0;
            if (lane < 32) {
                float q1 = v1 / mx;
                if (q1 > THRV)
                    for (int u = u0; u < TT; u += 2) out[rowbase + (size_t)u * CC + 64 + lane] = q1;
            }
        }
        // lens: both cycle vectors argmax-checked at tex-2 / tex-1; final.
    }

    if (w < 8 && lane == 0) lens[b0 + w] = (float)len;
}

extern "C" void kernel_launch(void* const* d_in, const int* in_sizes, int n_in,
                              void* d_out, int out_size, void* d_ws, size_t ws_size,
                              hipStream_t stream)
{
    const float* img = (const float*)d_in[0];
    const float* l1w = (const float*)d_in[1];
    const float* l1b = (const float*)d_in[2];
    const float* wih = (const float*)d_in[3];
    const float* whh = (const float*)d_in[4];
    const float* bih = (const float*)d_in[5];
    const float* bhh = (const float*)d_in[6];
    const float* l2w = (const float*)d_in[7];
    const float* l2b = (const float*)d_in[8];

    float* out  = (float*)d_out;
    float* lens = out + (size_t)2048 * TT * CC;

    // titles is ~99% zeros: clear everything, kernel scatters only survivors.
    hipMemsetAsync(d_out, 0, (size_t)out_size * sizeof(float), stream);

    gru_title<<<dim3(2048 / NB), dim3(1024), 0, stream>>>(
        img, l1w, l1b, wih, whh, bih, bhh, l2w, l2b, out, lens);
}